// Round 17
// baseline (39.578 us; speedup 1.0000x reference)
//
#include <hip/hip_runtime.h>
#include <stdint.h>

#define NIN 256
#define RPB 32              // rows per block: two 16-row MFMA tiles, row-paired
#define TWOLOG2E 2.8853900817779268f

typedef float    f32x4 __attribute__((ext_vector_type(4)));
typedef _Float16 half8 __attribute__((ext_vector_type(8)));
typedef __fp16   fp16x2 __attribute__((ext_vector_type(2)));
typedef uint32_t u32x4 __attribute__((ext_vector_type(4)));

#define SEL_LO 0x05040100u   // v_perm: lo fp16 halves (tile A rows 0..15)
#define SEL_HI 0x07060302u   // hi fp16 halves (tile B rows 16..31)

// tanh(x+b) = 1 - 2/(exp2((x+b)*2log2e)+1); bs = b*2log2e pre-scaled
static __device__ __forceinline__ float fast_tanh_b(float x, float bs) {
    float e = __builtin_amdgcn_exp2f(fmaf(x, TWOLOG2E, bs));
    return 1.0f - 2.0f * __builtin_amdgcn_rcpf(e + 1.0f);
}
static __device__ __forceinline__ unsigned pkrtz(float a, float b) {
    fp16x2 h = __builtin_amdgcn_cvt_pkrtz(a, b);    // lo=a (tile A), hi=b (tile B)
    return __builtin_bit_cast(unsigned, h);
}

// ---- prep: kt[lvl][g][q][n][e] = (fp16) K_lvl[g][ q*8+e ][ n ]  (identity k-order)
//      apre[lvl][g][f] = (col<<6) ^ (((col>>1)&3)<<4)   (row-pair layout byte base)
extern "C" __global__ void kprep_kernel(const float* __restrict__ k1, const float* __restrict__ k2,
                                        const float* __restrict__ k3, const float* __restrict__ k4,
                                        const int* __restrict__ i1, const int* __restrict__ i2,
                                        const int* __restrict__ i3, const int* __restrict__ i4,
                                        uint32_t* __restrict__ kt, int* __restrict__ apre) {
    const int bx  = blockIdx.x;                       // 16 blocks x 256
    const int lvl = bx >> 2;
    const float* Kp = (lvl == 0) ? k1 : (lvl == 1) ? k2 : (lvl == 2) ? k3 : k4;
    const int*   Ip = (lvl == 0) ? i1 : (lvl == 1) ? i2 : (lvl == 2) ? i3 : i4;
    const int sub = (bx & 3) * 256 + threadIdx.x;     // 0..1023 = g*64 + q*16 + n
    const int g = sub >> 6, q = (sub >> 4) & 3, n = sub & 15;
    const float* src = Kp + (size_t)(g * 32 + q * 8) * 16 + n;
    const float v0 = src[0],  v1 = src[16], v2 = src[32], v3 = src[48];
    const float v4 = src[64], v5 = src[80], v6 = src[96], v7 = src[112];
    u32x4 pk;
    pk.x = pkrtz(v0, v1); pk.y = pkrtz(v2, v3);
    pk.z = pkrtz(v4, v5); pk.w = pkrtz(v6, v7);
    *(u32x4*)(kt + (size_t)(lvl * 1024 + sub) * 4) = pk;

    if ((bx & 3) < 2) {                               // 512 idx entries per level
        const int f = (bx & 3) * 256 + threadIdx.x;
        const int col = Ip[f];
        apre[lvl * 512 + f] = (col << 6) ^ (((col >> 1) & 3) << 4);
    }
}

// ---- main ----
// ftile: col-major, 16 row-PAIRS per col (pair p = fp16 rows (p, p+16) in one u32):
//   byte(pair p, col) = (col<<6) ^ (((col>>1)&3)<<4) ^ (p<<2)
// One ds_read_b32 = A-frag element (row n) for BOTH 16-row tiles.
// 1024 threads = 16 waves, wave w owns group w; straight-line 4-level body;
// kt/bias hoisted; MFMA uses a shared zero C-quad; bias folded into tanh's fma.

extern "C" __global__ __launch_bounds__(1024, 8)
void denc_kernel(const float* __restrict__ x,
                 const int* __restrict__ a1, const float* __restrict__ b1,
                 const int* __restrict__ a2, const float* __restrict__ b2,
                 const int* __restrict__ a3, const float* __restrict__ b3,
                 const int* __restrict__ a4, const float* __restrict__ b4,
                 const uint32_t* __restrict__ kt,
                 float* __restrict__ out)
{
    __shared__ int4 ftile[4096];                     // 64 KB -> 2 blocks/CU
    const char* tfc = (const char*)ftile;

    const int tid  = threadIdx.x;
    const int w    = tid >> 6;                       // wave = group 0..15
    const int lane = tid & 63;
    const int q    = lane >> 4;                      // k-block / D row-quad
    const int n    = lane & 15;                      // A row-pair / B,D col
    const int R0   = blockIdx.x * RPB;
    const int Ln   = n << 2;                         // lane part of gather addr
    const int ki   = (w * 64 + q * 16 + n) * 4;      // kt dword base
    const int bi   = w * 16 + n;                     // bias index

    // ---- hoisted: all levels' K-fragments + pre-scaled biases ----
    const u32x4 bf1 = *(const u32x4*)(kt + ki);
    const u32x4 bf2 = *(const u32x4*)(kt + 4096 + ki);
    const u32x4 bf3 = *(const u32x4*)(kt + 8192 + ki);
    const u32x4 bf4 = *(const u32x4*)(kt + 12288 + ki);
    const float bs1 = b1[bi] * TWOLOG2E, bs2 = b2[bi] * TWOLOG2E;
    const float bs3 = b3[bi] * TWOLOG2E, bs4 = b4[bi] * TWOLOG2E;
    const f32x4 zq = {0.0f, 0.0f, 0.0f, 0.0f};       // shared MFMA C operand

    // ---- stage x: thread covers col c=tid&255, pair-quad j=tid>>8 ----
    {
        const int c = tid & 255;
        const int j = tid >> 8;                      // 0..3 -> pairs 4j..4j+3
        const float* xb = x + (size_t)R0 * 256 + c;
        uint32_t qp[4];
        #pragma unroll
        for (int k = 0; k < 4; ++k) {
            const int p = j * 4 + k;
            qp[k] = pkrtz(xb[(size_t)p * 256], xb[(size_t)(p + 16) * 256]);
        }
        const int s = (c >> 1) & 3;
        ftile[c * 4 + (j ^ s)] = make_int4((int)qp[0], (int)qp[1], (int)qp[2], (int)qp[3]);
    }

    // prefetch level-1 gather addresses
    int4 pa = *(const int4*)(a1 + w * 32 + q * 8);
    int4 pb = *(const int4*)(a1 + w * 32 + q * 8 + 4);

#define LEVEL(ApNext, BF, BS, OB, LAST) do { \
    __syncthreads(); \
    const uint32_t r0 = *(const uint32_t*)(tfc + (pa.x ^ Ln)); \
    const uint32_t r1 = *(const uint32_t*)(tfc + (pa.y ^ Ln)); \
    const uint32_t r2 = *(const uint32_t*)(tfc + (pa.z ^ Ln)); \
    const uint32_t r3 = *(const uint32_t*)(tfc + (pa.w ^ Ln)); \
    const uint32_t r4 = *(const uint32_t*)(tfc + (pb.x ^ Ln)); \
    const uint32_t r5 = *(const uint32_t*)(tfc + (pb.y ^ Ln)); \
    const uint32_t r6 = *(const uint32_t*)(tfc + (pb.z ^ Ln)); \
    const uint32_t r7 = *(const uint32_t*)(tfc + (pb.w ^ Ln)); \
    if (!(LAST)) {                                   /* rotate next level in */ \
        pa = *(const int4*)((ApNext) + w * 32 + q * 8); \
        pb = *(const int4*)((ApNext) + w * 32 + q * 8 + 4); \
    } \
    u32x4 fA, fB; \
    fA.x = __builtin_amdgcn_perm(r1, r0, SEL_LO); fB.x = __builtin_amdgcn_perm(r1, r0, SEL_HI); \
    fA.y = __builtin_amdgcn_perm(r3, r2, SEL_LO); fB.y = __builtin_amdgcn_perm(r3, r2, SEL_HI); \
    fA.z = __builtin_amdgcn_perm(r5, r4, SEL_LO); fB.z = __builtin_amdgcn_perm(r5, r4, SEL_HI); \
    fA.w = __builtin_amdgcn_perm(r7, r6, SEL_LO); fB.w = __builtin_amdgcn_perm(r7, r6, SEL_HI); \
    const f32x4 accA = __builtin_amdgcn_mfma_f32_16x16x32_f16( \
        __builtin_bit_cast(half8, fA), __builtin_bit_cast(half8, (BF)), zq, 0, 0, 0); \
    const f32x4 accB = __builtin_amdgcn_mfma_f32_16x16x32_f16( \
        __builtin_bit_cast(half8, fB), __builtin_bit_cast(half8, (BF)), zq, 0, 0, 0); \
    const float bs = (BS); \
    const float tA0 = fast_tanh_b(accA[0], bs), tA1 = fast_tanh_b(accA[1], bs); \
    const float tA2 = fast_tanh_b(accA[2], bs), tA3 = fast_tanh_b(accA[3], bs); \
    const float tB0 = fast_tanh_b(accB[0], bs), tB1 = fast_tanh_b(accB[1], bs); \
    const float tB2 = fast_tanh_b(accB[2], bs), tB3 = fast_tanh_b(accB[3], bs); \
    if (LAST) { \
        float* ob = out + (size_t)(R0 + q * 4) * 256 + bi; \
        ob[0]    = tA0; ob[256]  = tA1; ob[512]  = tA2; ob[768]  = tA3; \
        ob[4096] = tB0; ob[4352] = tB1; ob[4608] = tB2; ob[4864] = tB3; \
    } else { \
        const int col = (OB) + bi; \
        const int s = (col >> 1) & 3; \
        ftile[col * 4 + (q ^ s)] = make_int4( \
            (int)pkrtz(tA0, tB0), (int)pkrtz(tA1, tB1), \
            (int)pkrtz(tA2, tB2), (int)pkrtz(tA3, tB3)); \
    } \
} while (0)

    LEVEL(a2, bf1, bs1, NIN,       0);
    LEVEL(a3, bf2, bs2, NIN + 256, 0);
    LEVEL(a4, bf3, bs3, NIN + 512, 0);
    LEVEL(a4, bf4, bs4, 0,         1);

#undef LEVEL
}

extern "C" void kernel_launch(void* const* d_in, const int* in_sizes, int n_in,
                              void* d_out, int out_size, void* d_ws, size_t ws_size,
                              hipStream_t stream) {
    const float* x  = (const float*)d_in[0];
    const float* k1 = (const float*)d_in[1];
    const float* b1 = (const float*)d_in[2];
    const int*   i1 = (const int*)  d_in[3];
    const float* k2 = (const float*)d_in[4];
    const float* b2 = (const float*)d_in[5];
    const int*   i2 = (const int*)  d_in[6];
    const float* k3 = (const float*)d_in[7];
    const float* b3 = (const float*)d_in[8];
    const int*   i3 = (const int*)  d_in[9];
    const float* k4 = (const float*)d_in[10];
    const float* b4 = (const float*)d_in[11];
    const int*   i4 = (const int*)  d_in[12];
    float* out = (float*)d_out;
    uint32_t* kt = (uint32_t*)d_ws;                  // 64 KB
    int* apre = (int*)((char*)d_ws + 65536);         // 8 KB

    hipLaunchKernelGGL(kprep_kernel, dim3(16), dim3(256), 0, stream,
                       k1, k2, k3, k4, i1, i2, i3, i4, kt, apre);

    const int batch = in_sizes[0] / NIN;             // 65536
    hipLaunchKernelGGL(denc_kernel, dim3(batch / RPB), dim3(1024), 0, stream,
                       x, apre, b1, apre + 512, b2, apre + 1024, b3, apre + 1536, b4,
                       (const uint32_t*)kt, out);
}

// Round 18
// 37.935 us; speedup vs baseline: 1.0433x; 1.0433x over previous
//
#include <hip/hip_runtime.h>
#include <stdint.h>

#define NIN 256
#define RPB 32              // rows per block: two 16-row MFMA tiles, row-paired
#define TWOLOG2E 2.8853900817779268f

typedef float    f32x4 __attribute__((ext_vector_type(4)));
typedef _Float16 half8 __attribute__((ext_vector_type(8)));
typedef __fp16   fp16x2 __attribute__((ext_vector_type(2)));
typedef uint32_t u32x4 __attribute__((ext_vector_type(4)));

#define SEL_LO 0x05040100u   // v_perm: lo fp16 halves (tile A rows 0..15)
#define SEL_HI 0x07060302u   // hi fp16 halves (tile B rows 16..31)

// tanh(x+b) = 1 - 2/(exp2((x+b)*2log2e)+1); bs = b*2log2e pre-scaled
static __device__ __forceinline__ float fast_tanh_b(float x, float bs) {
    float e = __builtin_amdgcn_exp2f(fmaf(x, TWOLOG2E, bs));
    return 1.0f - 2.0f * __builtin_amdgcn_rcpf(e + 1.0f);
}
static __device__ __forceinline__ unsigned pkrtz(float a, float b) {
    fp16x2 h = __builtin_amdgcn_cvt_pkrtz(a, b);    // lo=a (tile A), hi=b (tile B)
    return __builtin_bit_cast(unsigned, h);
}

// ---- prep: kt[lvl][g][q][n][e] = (fp16) K_lvl[g][ q*8+e ][ n ]  (identity k-order)
//      apre[lvl][g][f] = (col<<6) ^ (((col>>1)&3)<<4)   (row-pair layout byte base)
extern "C" __global__ void kprep_kernel(const float* __restrict__ k1, const float* __restrict__ k2,
                                        const float* __restrict__ k3, const float* __restrict__ k4,
                                        const int* __restrict__ i1, const int* __restrict__ i2,
                                        const int* __restrict__ i3, const int* __restrict__ i4,
                                        uint32_t* __restrict__ kt, int* __restrict__ apre) {
    const int bx  = blockIdx.x;                       // 16 blocks x 256
    const int lvl = bx >> 2;
    const float* Kp = (lvl == 0) ? k1 : (lvl == 1) ? k2 : (lvl == 2) ? k3 : k4;
    const int*   Ip = (lvl == 0) ? i1 : (lvl == 1) ? i2 : (lvl == 2) ? i3 : i4;
    const int sub = (bx & 3) * 256 + threadIdx.x;     // 0..1023 = g*64 + q*16 + n
    const int g = sub >> 6, q = (sub >> 4) & 3, n = sub & 15;
    const float* src = Kp + (size_t)(g * 32 + q * 8) * 16 + n;
    const float v0 = src[0],  v1 = src[16], v2 = src[32], v3 = src[48];
    const float v4 = src[64], v5 = src[80], v6 = src[96], v7 = src[112];
    u32x4 pk;
    pk.x = pkrtz(v0, v1); pk.y = pkrtz(v2, v3);
    pk.z = pkrtz(v4, v5); pk.w = pkrtz(v6, v7);
    *(u32x4*)(kt + (size_t)(lvl * 1024 + sub) * 4) = pk;

    if ((bx & 3) < 2) {                               // 512 idx entries per level
        const int f = (bx & 3) * 256 + threadIdx.x;
        const int col = Ip[f];
        apre[lvl * 512 + f] = (col << 6) ^ (((col >> 1) & 3) << 4);
    }
}

// ---- main ----
// ftile: col-major, 16 row-PAIRS per col (pair p = fp16 rows (p, p+16) in one u32):
//   byte(pair p, col) = (col<<6) ^ (((col>>1)&3)<<4) ^ (p<<2)
// One ds_read_b32 = A-frag element (row n) for BOTH 16-row tiles.
// 1024 threads = 16 waves, wave w owns group w; straight-line 4-level body;
// kt/bias hoisted; setprio(1) around the compute cluster so this block's
// compute-phase waves preempt the co-resident block's stage/gather waves (T5).

extern "C" __global__ __launch_bounds__(1024, 8)
void denc_kernel(const float* __restrict__ x,
                 const int* __restrict__ a1, const float* __restrict__ b1,
                 const int* __restrict__ a2, const float* __restrict__ b2,
                 const int* __restrict__ a3, const float* __restrict__ b3,
                 const int* __restrict__ a4, const float* __restrict__ b4,
                 const uint32_t* __restrict__ kt,
                 float* __restrict__ out)
{
    __shared__ int4 ftile[4096];                     // 64 KB -> 2 blocks/CU
    const char* tfc = (const char*)ftile;

    const int tid  = threadIdx.x;
    const int w    = tid >> 6;                       // wave = group 0..15
    const int lane = tid & 63;
    const int q    = lane >> 4;                      // k-block / D row-quad
    const int n    = lane & 15;                      // A row-pair / B,D col
    const int R0   = blockIdx.x * RPB;
    const int Ln   = n << 2;                         // lane part of gather addr
    const int ki   = (w * 64 + q * 16 + n) * 4;      // kt dword base
    const int bi   = w * 16 + n;                     // bias index

    // ---- hoisted: all levels' K-fragments + pre-scaled biases ----
    const u32x4 bf1 = *(const u32x4*)(kt + ki);
    const u32x4 bf2 = *(const u32x4*)(kt + 4096 + ki);
    const u32x4 bf3 = *(const u32x4*)(kt + 8192 + ki);
    const u32x4 bf4 = *(const u32x4*)(kt + 12288 + ki);
    const float bs1 = b1[bi] * TWOLOG2E, bs2 = b2[bi] * TWOLOG2E;
    const float bs3 = b3[bi] * TWOLOG2E, bs4 = b4[bi] * TWOLOG2E;
    const f32x4 zq = {0.0f, 0.0f, 0.0f, 0.0f};       // shared MFMA C operand

    // ---- stage x: thread covers col c=tid&255, pair-quad j=tid>>8 ----
    {
        const int c = tid & 255;
        const int j = tid >> 8;                      // 0..3 -> pairs 4j..4j+3
        const float* xb = x + (size_t)R0 * 256 + c;
        uint32_t qp[4];
        #pragma unroll
        for (int k = 0; k < 4; ++k) {
            const int p = j * 4 + k;
            qp[k] = pkrtz(xb[(size_t)p * 256], xb[(size_t)(p + 16) * 256]);
        }
        const int s = (c >> 1) & 3;
        ftile[c * 4 + (j ^ s)] = make_int4((int)qp[0], (int)qp[1], (int)qp[2], (int)qp[3]);
    }

    // prefetch level-1 gather addresses
    int4 pa = *(const int4*)(a1 + w * 32 + q * 8);
    int4 pb = *(const int4*)(a1 + w * 32 + q * 8 + 4);

#define LEVEL(ApNext, BF, BS, OB, LAST) do { \
    __syncthreads(); \
    const uint32_t r0 = *(const uint32_t*)(tfc + (pa.x ^ Ln)); \
    const uint32_t r1 = *(const uint32_t*)(tfc + (pa.y ^ Ln)); \
    const uint32_t r2 = *(const uint32_t*)(tfc + (pa.z ^ Ln)); \
    const uint32_t r3 = *(const uint32_t*)(tfc + (pa.w ^ Ln)); \
    const uint32_t r4 = *(const uint32_t*)(tfc + (pb.x ^ Ln)); \
    const uint32_t r5 = *(const uint32_t*)(tfc + (pb.y ^ Ln)); \
    const uint32_t r6 = *(const uint32_t*)(tfc + (pb.z ^ Ln)); \
    const uint32_t r7 = *(const uint32_t*)(tfc + (pb.w ^ Ln)); \
    if (!(LAST)) {                                   /* rotate next level in */ \
        pa = *(const int4*)((ApNext) + w * 32 + q * 8); \
        pb = *(const int4*)((ApNext) + w * 32 + q * 8 + 4); \
    } \
    __builtin_amdgcn_s_setprio(1);                   /* compute cluster (T5) */ \
    u32x4 fA, fB; \
    fA.x = __builtin_amdgcn_perm(r1, r0, SEL_LO); fB.x = __builtin_amdgcn_perm(r1, r0, SEL_HI); \
    fA.y = __builtin_amdgcn_perm(r3, r2, SEL_LO); fB.y = __builtin_amdgcn_perm(r3, r2, SEL_HI); \
    fA.z = __builtin_amdgcn_perm(r5, r4, SEL_LO); fB.z = __builtin_amdgcn_perm(r5, r4, SEL_HI); \
    fA.w = __builtin_amdgcn_perm(r7, r6, SEL_LO); fB.w = __builtin_amdgcn_perm(r7, r6, SEL_HI); \
    const f32x4 accA = __builtin_amdgcn_mfma_f32_16x16x32_f16( \
        __builtin_bit_cast(half8, fA), __builtin_bit_cast(half8, (BF)), zq, 0, 0, 0); \
    const f32x4 accB = __builtin_amdgcn_mfma_f32_16x16x32_f16( \
        __builtin_bit_cast(half8, fB), __builtin_bit_cast(half8, (BF)), zq, 0, 0, 0); \
    const float bs = (BS); \
    const float tA0 = fast_tanh_b(accA[0], bs), tA1 = fast_tanh_b(accA[1], bs); \
    const float tA2 = fast_tanh_b(accA[2], bs), tA3 = fast_tanh_b(accA[3], bs); \
    const float tB0 = fast_tanh_b(accB[0], bs), tB1 = fast_tanh_b(accB[1], bs); \
    const float tB2 = fast_tanh_b(accB[2], bs), tB3 = fast_tanh_b(accB[3], bs); \
    if (LAST) { \
        float* ob = out + (size_t)(R0 + q * 4) * 256 + bi; \
        ob[0]    = tA0; ob[256]  = tA1; ob[512]  = tA2; ob[768]  = tA3; \
        ob[4096] = tB0; ob[4352] = tB1; ob[4608] = tB2; ob[4864] = tB3; \
    } else { \
        const int col = (OB) + bi; \
        const int s = (col >> 1) & 3; \
        ftile[col * 4 + (q ^ s)] = make_int4( \
            (int)pkrtz(tA0, tB0), (int)pkrtz(tA1, tB1), \
            (int)pkrtz(tA2, tB2), (int)pkrtz(tA3, tB3)); \
    } \
    __builtin_amdgcn_s_setprio(0); \
} while (0)

    LEVEL(a2, bf1, bs1, NIN,       0);
    LEVEL(a3, bf2, bs2, NIN + 256, 0);
    LEVEL(a4, bf3, bs3, NIN + 512, 0);
    LEVEL(a4, bf4, bs4, 0,         1);

#undef LEVEL
}

extern "C" void kernel_launch(void* const* d_in, const int* in_sizes, int n_in,
                              void* d_out, int out_size, void* d_ws, size_t ws_size,
                              hipStream_t stream) {
    const float* x  = (const float*)d_in[0];
    const float* k1 = (const float*)d_in[1];
    const float* b1 = (const float*)d_in[2];
    const int*   i1 = (const int*)  d_in[3];
    const float* k2 = (const float*)d_in[4];
    const float* b2 = (const float*)d_in[5];
    const int*   i2 = (const int*)  d_in[6];
    const float* k3 = (const float*)d_in[7];
    const float* b3 = (const float*)d_in[8];
    const int*   i3 = (const int*)  d_in[9];
    const float* k4 = (const float*)d_in[10];
    const float* b4 = (const float*)d_in[11];
    const int*   i4 = (const int*)  d_in[12];
    float* out = (float*)d_out;
    uint32_t* kt = (uint32_t*)d_ws;                  // 64 KB
    int* apre = (int*)((char*)d_ws + 65536);         // 8 KB

    hipLaunchKernelGGL(kprep_kernel, dim3(16), dim3(256), 0, stream,
                       k1, k2, k3, k4, i1, i2, i3, i4, kt, apre);

    const int batch = in_sizes[0] / NIN;             // 65536
    hipLaunchKernelGGL(denc_kernel, dim3(batch / RPB), dim3(1024), 0, stream,
                       x, apre, b1, apre + 512, b2, apre + 1024, b3, apre + 1536, b4,
                       (const uint32_t*)kt, out);
}